// Round 5
// baseline (276.937 us; speedup 1.0000x reference)
//
#include <hip/hip_runtime.h>
#include <math.h>

// ObjectosphereLoss — single-pass fused kernel.
//   sm = softmax(logits); lsm = log(sm + 1e-10)
//   unknown: jr = -(1/12)*sum(lsm) + 1e-4*||f||^2
//   known:   jr = -lsm[y]          + 1e-4*max(10-||f||,0)^2
//   loss = sum(w[y]*jr)/sum(w[y])
//
// Max-free softmax (|logit| small) + algebraic sums:
//   sum(lsm) = sum(x) - 13*log(S);  lsm[y] = x[y] - log(S)   (eps negligible)
//
// Each wave owns 32 CONTIGUOUS rows. All small inputs (logits/ty/unk/weights)
// staged ONCE per wave (2 big loads + LDS / lane registers) so the row loop
// issues only the two coalesced non-temporal float4 feature loads -> clean
// HBM request stream. Finalize merged via last-block atomic-counter pattern.

typedef float f32x4 __attribute__((ext_vector_type(4)));   // true clang vector
                                                           // (nontemporal ok)
constexpr int   CLS  = 13;
constexpr float INV_KNOWN = 1.0f / 12.0f;
constexpr float LAM  = 1e-4f;
constexpr float XI   = 10.0f;

constexpr int RPW   = 32;            // rows per wave (contiguous)
constexpr int BLOCK = 256;           // 4 waves
constexpr int WPB   = BLOCK / 64;
constexpr size_t COUNTER_OFF = 1u << 20;   // counter at 1 MB into d_ws

__global__ __launch_bounds__(256, 8) void obj_main(
    const float*  __restrict__ logits,
    const int*    __restrict__ true_y,
    const int*    __restrict__ is_unknown,
    const f32x4*  __restrict__ feat,
    const float*  __restrict__ weights,
    double*       __restrict__ partials,   // [2 * gridDim.x]
    unsigned*     __restrict__ counter,    // zeroed by memset node each launch
    float*        __restrict__ out,
    int B)
{
    const int lane = threadIdx.x & 63;
    const int wid  = threadIdx.x >> 6;
    const int gw   = blockIdx.x * WPB + wid;
    const int base_row = gw * RPW;

    __shared__ float s_log[WPB][512];

    // ---- one-time staging of small inputs (per wave) ----
    {
        const size_t lbase = (size_t)base_row * CLS;       // 416 floats needed
        const size_t ltot  = (size_t)B * CLS;
        size_t i0 = lbase + (size_t)lane * 4;
        size_t i1 = i0 + 256;
        f32x4 v0 = (f32x4)0.0f, v1 = (f32x4)0.0f;
        if (i0 + 4 <= ltot) v0 = *reinterpret_cast<const f32x4*>(logits + i0);
        if (i1 + 4 <= ltot) v1 = *reinterpret_cast<const f32x4*>(logits + i1);
        *reinterpret_cast<f32x4*>(&s_log[wid][lane * 4])       = v0;
        *reinterpret_cast<f32x4*>(&s_log[wid][256 + lane * 4]) = v1;
    }
    int r_ld = base_row + (lane & 31); if (r_ld >= B) r_ld = B - 1;
    const int   tyv  = true_y[r_ld];        // lane rl holds row base+rl's label
    const int   unkv = is_unknown[r_ld];
    const float wv   = weights[lane < CLS ? lane : 0];
    __syncthreads();

    // ---- row loop: only VMEM = 2 nt float4 loads per row ----
    double num = 0.0, den = 0.0;
    int row = base_row;
    f32x4 a = (f32x4)0.0f, b = (f32x4)0.0f;
    if (row < B) {
        const f32x4* fr = feat + (size_t)row * 128;
        a = __builtin_nontemporal_load(fr + lane);
        b = __builtin_nontemporal_load(fr + lane + 64);
    }

    for (int rl = 0; rl < RPW && row < B; ++rl) {
        // prefetch next (contiguous) row
        f32x4 na = (f32x4)0.0f, nb = (f32x4)0.0f;
        const int nrow = row + 1;
        if (rl + 1 < RPW && nrow < B) {
            const f32x4* fr = feat + (size_t)nrow * 128;
            na = __builtin_nontemporal_load(fr + lane);
            nb = __builtin_nontemporal_load(fr + lane + 64);
        }

        float ss = fmaf(a.x, a.x, fmaf(a.y, a.y, fmaf(a.z, a.z, a.w * a.w)))
                 + fmaf(b.x, b.x, fmaf(b.y, b.y, fmaf(b.z, b.z, b.w * b.w)));

        const float x = (lane < CLS) ? s_log[wid][rl * CLS + lane] : 0.0f;
        const float e = (lane < CLS) ? __expf(x) : 0.0f;
        float S = e, sx = x;

        // ss: full 64-lane butterfly (6 steps)
        #pragma unroll
        for (int o = 32; o; o >>= 1) ss += __shfl_xor(ss, o, 64);
        // S, sx: nonzero only on lanes <13 -> 16-lane butterfly (4 steps);
        // group-0 lanes (0..15) end with the full sums, lane 0 is what counts.
        #pragma unroll
        for (int o = 8; o; o >>= 1) {
            S  += __shfl_xor(S,  o, 64);
            sx += __shfl_xor(sx, o, 64);
        }

        const int   ty   = __shfl(tyv,  rl, 64);
        const int   unk  = __shfl(unkv, rl, 64);
        const float w    = __shfl(wv,   ty, 64);
        const float x_ty = __shfl(x,    ty, 64);
        const float logS = __logf(S);
        const float mag  = sqrtf(ss);

        const float jr_u = fmaf(LAM, ss, -INV_KNOWN * (sx - (float)CLS * logS));
        const float dk   = fmaxf(XI - mag, 0.0f);
        const float jr_k = fmaf(LAM, dk * dk, logS - x_ty);
        const float jr   = unk ? jr_u : jr_k;

        num += (double)(w * jr);     // only lane 0's copy is consumed
        den += (double)w;

        row = nrow; a = na; b = nb;
    }

    // ---- block reduce (lane 0 of each wave holds valid sums) ----
    __shared__ double s_n[WPB], s_d[WPB];
    __shared__ unsigned s_last;
    if (lane == 0) { s_n[wid] = num; s_d[wid] = den; }
    __syncthreads();
    if (threadIdx.x == 0) {
        double n = 0.0, d = 0.0;
        for (int i = 0; i < WPB; ++i) { n += s_n[i]; d += s_d[i]; }
        __hip_atomic_store(&partials[blockIdx.x], n,
                           __ATOMIC_RELAXED, __HIP_MEMORY_SCOPE_AGENT);
        __hip_atomic_store(&partials[gridDim.x + blockIdx.x], d,
                           __ATOMIC_RELAXED, __HIP_MEMORY_SCOPE_AGENT);
        __threadfence();
        unsigned old = __hip_atomic_fetch_add(counter, 1u,
                           __ATOMIC_ACQ_REL, __HIP_MEMORY_SCOPE_AGENT);
        s_last = (old == gridDim.x - 1) ? 1u : 0u;
    }
    __syncthreads();

    // ---- last block finalizes ----
    if (s_last) {
        __threadfence();
        double n = 0.0, d = 0.0;
        for (int i = threadIdx.x; i < (int)gridDim.x; i += blockDim.x) {
            n += __hip_atomic_load(&partials[i],
                     __ATOMIC_RELAXED, __HIP_MEMORY_SCOPE_AGENT);
            d += __hip_atomic_load(&partials[gridDim.x + i],
                     __ATOMIC_RELAXED, __HIP_MEMORY_SCOPE_AGENT);
        }
        #pragma unroll
        for (int o = 32; o; o >>= 1) {
            n += __shfl_xor(n, o, 64);
            d += __shfl_xor(d, o, 64);
        }
        double* s_fd = (double*)&s_log[0][0];   // reuse LDS
        if (lane == 0) { s_fd[wid] = n; s_fd[WPB + wid] = d; }
        __syncthreads();
        if (threadIdx.x == 0) {
            double tn = 0.0, td = 0.0;
            for (int i = 0; i < WPB; ++i) { tn += s_fd[i]; td += s_fd[WPB + i]; }
            out[0] = (float)(tn / td);
        }
    }
}

extern "C" void kernel_launch(void* const* d_in, const int* in_sizes, int n_in,
                              void* d_out, int out_size, void* d_ws, size_t ws_size,
                              hipStream_t stream)
{
    const float*  logits     = (const float*)d_in[0];
    const int*    true_y     = (const int*)d_in[1];
    const int*    is_unknown = (const int*)d_in[2];
    const f32x4*  feat       = (const f32x4*)d_in[3];
    const float*  weights    = (const float*)d_in[4];
    float*        out        = (float*)d_out;
    const int B = in_sizes[1];                 // 262144 rows

    const int grid = (B + WPB * RPW - 1) / (WPB * RPW);   // 2048
    double*   partials = (double*)d_ws;                    // 2*grid doubles
    unsigned* counter  = (unsigned*)((char*)d_ws + COUNTER_OFF);

    (void)hipMemsetAsync(counter, 0, sizeof(unsigned), stream);
    obj_main<<<grid, BLOCK, 0, stream>>>(logits, true_y, is_unknown, feat,
                                         weights, partials, counter, out, B);
}